// Round 9
// baseline (147.350 us; speedup 1.0000x reference)
//
#include <hip/hip_runtime.h>
#include <math.h>

#define NJ 140
#define NV 13059
#define NB 512
#define NBONES 28

#define MTILES 103                    // 103*128 = 13184 >= NV
#define NBLK 12                       // 1536 / 128
#define KS 18                         // K = 576 = 18*32 (32-k panels in ws)
#define KS2 9                         // merged K-steps (BK=64)
#define GRID_GEMM (MTILES*NBLK)       // 1236

#define APREP_SLOTS (MTILES*KS*512)   // 949248 f16x8 slots

typedef _Float16 f16x8 __attribute__((ext_vector_type(8)));
typedef float    f32x4 __attribute__((ext_vector_type(4)));

// async global->LDS DMA, 16 B per lane; lds base must be wave-uniform
#define GL16(gp, lp) __builtin_amdgcn_global_load_lds( \
    (const __attribute__((address_space(1))) unsigned int*)(gp), \
    (__attribute__((address_space(3))) unsigned int*)(lp), 16, 0, 0)

// ---------------- Kernel 1: fused prep (kin + A-prep), R6-proven -----------
// Panel layout (both A and B), bank-swizzled for conflict-free ds_read_b128:
// panel[tile][ks][slot = row*4 + cs][8 f16], slot cs holds chunk
// ci = cs ^ ((row>>1)&3), i.e. elements [row][k = ks*32 + ci*8 .. +7].
// blocks [0,NB): kinematics for batch b -> packed B panels + jout
// blocks [NB, NB+MTILES*KS): A[v][k] = w[v,j]*{x,y,z,1}, one (mt,ks) per block
__global__ __launch_bounds__(256) void prep_kernel(
    const float* __restrict__ pose,         // (NB, NJ*3)
    const float* __restrict__ bone_lengths, // (NB, NBONES)
    const float* __restrict__ cbl,          // (NB)
    const float* __restrict__ trans,        // (NB, 3)
    const float* __restrict__ scale,        // (NB)
    const float* __restrict__ v_template,   // (NV, 3)
    const float* __restrict__ t_pose,       // (NJ, 3)
    const int*   __restrict__ parent,       // (NJ)
    const int*   __restrict__ bone_mapper,  // (NJ)
    const float* __restrict__ weights,      // (NV, NJ)
    _Float16* __restrict__ Ap,              // ws: (MTILES, KS, 512, 8)
    _Float16* __restrict__ Bp,              // ws: (NBLK, KS, 512, 8)
    float* __restrict__ jout)               // (NB, NJ, 3)
{
    const int t = threadIdx.x;

    if (blockIdx.x >= NB) {
        // ---- A prep: one (mt, ks) panel slice per block ----
        const int id  = blockIdx.x - NB;       // = mt*KS + ks
        const int mt  = id / KS;
        const int ks  = id - mt*KS;
        const int row = t >> 1;
        const int q   = t & 1;
        const int v   = mt*128 + row;
        const int j0  = ks*8 + q*4;
        const int s   = (row >> 1) & 3;

        f16x8 oA, oB;                          // chunks ci=2q and ci=2q+1
        #pragma unroll
        for (int i = 0; i < 8; ++i) { oA[i] = (_Float16)0.f; oB[i] = (_Float16)0.f; }

        if (v < NV && j0 + 3 < NJ) {           // NJ%8==4 -> per-quad all-or-nothing
            float xv = v_template[v*3+0];
            float yv = v_template[v*3+1];
            float zv = v_template[v*3+2];
            const float4 w4 = *(const float4*)(weights + (size_t)v*NJ + j0);
            oA[0] = (_Float16)(w4.x*xv); oA[1] = (_Float16)(w4.x*yv);
            oA[2] = (_Float16)(w4.x*zv); oA[3] = (_Float16)w4.x;
            oA[4] = (_Float16)(w4.y*xv); oA[5] = (_Float16)(w4.y*yv);
            oA[6] = (_Float16)(w4.y*zv); oA[7] = (_Float16)w4.y;
            oB[0] = (_Float16)(w4.z*xv); oB[1] = (_Float16)(w4.z*yv);
            oB[2] = (_Float16)(w4.z*zv); oB[3] = (_Float16)w4.z;
            oB[4] = (_Float16)(w4.w*xv); oB[5] = (_Float16)(w4.w*yv);
            oB[6] = (_Float16)(w4.w*zv); oB[7] = (_Float16)w4.w;
        }
        // slot cs holds chunk ci = cs ^ s  => cs(2q)=2q^s, cs(2q+1)=cs(2q)^1
        const int base = ((2*q) ^ s) & ~1;     // even slot of the pair
        _Float16* dst = Ap + (((size_t)id)*512 + row*4 + base)*8;
        if (s & 1) {                            // cs(2q) is odd
            *(f16x8*)dst       = oB;            // even slot = cs(2q+1)
            *(f16x8*)(dst + 8) = oA;            // odd slot  = cs(2q)
        } else {
            *(f16x8*)dst       = oA;
            *(f16x8*)(dst + 8) = oB;
        }
        return;
    }

    // ---- kinematics for batch b = blockIdx.x ----
    __shared__ float M0[NJ][12];
    __shared__ float M1[NJ][12];
    __shared__ int   a0[NJ];
    __shared__ int   a1[NJ];

    const int b = blockIdx.x;

    if (t < NJ) {
        const int j = t;
        float z = pose[b*(NJ*3) + 3*j + 0];
        float y = pose[b*(NJ*3) + 3*j + 1];
        float x = pose[b*(NJ*3) + 3*j + 2];
        float cx = cosf(x), sx = sinf(x);
        float cy = cosf(y), sy = sinf(y);
        float cz = cosf(z), sz = sinf(z);
        float r00 = cz*cy;
        float r01 = cz*sy*sx - sz*cx;
        float r02 = cz*sy*cx + sz*sx;
        float r10 = sz*cy;
        float r11 = sz*sy*sx + cz*cx;
        float r12 = sz*sy*cx - cz*sx;
        float r20 = -sy;
        float r21 = cy*sx;
        float r22 = cy*cx;
        float t0, t1, t2;
        int p = parent[j];
        if (j == 0) {
            t0 = t_pose[0]; t1 = t_pose[1]; t2 = t_pose[2];
        } else {
            float ox = t_pose[3*j+0] - t_pose[3*p+0];
            float oy = t_pose[3*j+1] - t_pose[3*p+1];
            float oz = t_pose[3*j+2] - t_pose[3*p+2];
            float s;
            if (j == 1) {
                s = cbl[b];
            } else {
                int blid = bone_mapper[j];
                if (blid >= 0) {
                    float bv = bone_lengths[b*NBONES + blid];
                    s = 2.0f / (1.0f + expf(-bv*0.2f));   // 2*sigmoid(x/5)
                } else {
                    s = 1.0f;
                }
            }
            t0 = ox*s; t1 = oy*s; t2 = oz*s;
        }
        M0[j][0]=r00; M0[j][1]=r01; M0[j][2]=r02;  M0[j][3]=t0;
        M0[j][4]=r10; M0[j][5]=r11; M0[j][6]=r12;  M0[j][7]=t1;
        M0[j][8]=r20; M0[j][9]=r21; M0[j][10]=r22; M0[j][11]=t2;
        a0[j] = (j == 0) ? -1 : p;
    }
    __syncthreads();

    float* src = &M0[0][0]; float* dst = &M1[0][0];
    int* as = a0; int* ad = a1;
    for (int r = 0; r < 8; ++r) {
        if (t < NJ) {
            int a = as[t];
            const float* Mi = src + t*12;
            float* Do = dst + t*12;
            if (a >= 0) {
                const float* Mp = src + a*12;
                #pragma unroll
                for (int m = 0; m < 3; ++m) {
                    float p0 = Mp[m*4+0], p1 = Mp[m*4+1], p2 = Mp[m*4+2], p3 = Mp[m*4+3];
                    Do[m*4+0] = p0*Mi[0] + p1*Mi[4] + p2*Mi[8];
                    Do[m*4+1] = p0*Mi[1] + p1*Mi[5] + p2*Mi[9];
                    Do[m*4+2] = p0*Mi[2] + p1*Mi[6] + p2*Mi[10];
                    Do[m*4+3] = p0*Mi[3] + p1*Mi[7] + p2*Mi[11] + p3;
                }
                ad[t] = as[a];
            } else {
                #pragma unroll
                for (int e = 0; e < 12; ++e) Do[e] = Mi[e];
                ad[t] = -1;
            }
        }
        __syncthreads();
        float* tf = src; src = dst; dst = tf;
        int* ti = as; as = ad; ad = ti;
    }

    // G_rel (fp32) into the spare LDS buffer, then pack to B panels
    float* grl = dst;   // dst != src after even # of swaps
    if (t < NJ) {
        const int j = t;
        const float* G = src + j*12;
        float sb = scale[b];
        float tr0 = trans[b*3+0], tr1 = trans[b*3+1], tr2 = trans[b*3+2];
        float* jo = jout + ((size_t)b*NJ + j)*3;
        jo[0] = G[3]*sb  + tr0;
        jo[1] = G[7]*sb  + tr1;
        jo[2] = G[11]*sb + tr2;
        float jx = t_pose[3*j+0], jy = t_pose[3*j+1], jz = t_pose[3*j+2];
        #pragma unroll
        for (int c = 0; c < 3; ++c) {
            float g0 = G[c*4+0], g1 = G[c*4+1], g2 = G[c*4+2];
            float g3 = G[c*4+3] - (g0*jx + g1*jy + g2*jz);
            grl[j*12 + c*4 + 0] = g0;
            grl[j*12 + c*4 + 1] = g1;
            grl[j*12 + c*4 + 2] = g2;
            grl[j*12 + c*4 + 3] = g3;
        }
    }
    __syncthreads();

    // pack: 3 rows x 18 ks x 4 ci = 216 f16x8 slots (swizzled)
    if (t < 216) {
        int c  = t / 72;
        int rr = t - c*72;
        int ks = rr >> 2;
        int ci = rr & 3;
        int nrow = b*3 + c;
        int nbp = nrow >> 7;
        int rl = nrow & 127;
        int j0 = ks*8 + ci*2;
        f16x8 o;
        #pragma unroll
        for (int i = 0; i < 8; ++i) o[i] = (_Float16)0.f;
        if (j0 < NJ) {
            o[0] = (_Float16)grl[j0*12 + c*4 + 0];
            o[1] = (_Float16)grl[j0*12 + c*4 + 1];
            o[2] = (_Float16)grl[j0*12 + c*4 + 2];
            o[3] = (_Float16)grl[j0*12 + c*4 + 3];
        }
        if (j0 + 1 < NJ) {
            o[4] = (_Float16)grl[(j0+1)*12 + c*4 + 0];
            o[5] = (_Float16)grl[(j0+1)*12 + c*4 + 1];
            o[6] = (_Float16)grl[(j0+1)*12 + c*4 + 2];
            o[7] = (_Float16)grl[(j0+1)*12 + c*4 + 3];
        }
        int cs = ci ^ ((rl >> 1) & 3);
        *(f16x8*)(Bp + ((size_t)(nbp*KS + ks)*512 + rl*4 + cs)*8) = o;
    }
}

// ---------------- Kernel 2: BK=64 merged-step ring GEMM --------------------
// 1236 blocks x 512 thr (8 waves 2m x 4n), tile 128x128, BK=64, 9 K-steps.
// R8 analysis: ~60% of the gemm wall is per-step boundary cost (barrier
// convergence + waitcnt + convoy), paid 18x. This halves it to 9x: each
// merged step stages/computes TWO 32-k panels; no barrier between halves,
// so the compiler pipelines half-1 ds_reads under half-0 MFMAs.
// Buffers 16 KB: A 3-ring (lead-2) + B 2-ring (lead-1) = 80 KB -> exactly
// 2 blocks/CU (16 waves). Counted vmcnt(2) mid-loop (never 0) as in R6.
// Ap/Bp layouts and the prep kernel are unchanged (a merged buffer is just
// two consecutive 8 KB ks-panels staged contiguously).
__global__ __launch_bounds__(512, 4) void gemm_kernel(
    const _Float16* __restrict__ Ap,       // (MTILES, KS, 512, 8)
    const _Float16* __restrict__ Bp,       // (NBLK, KS, 512, 8)
    const float* __restrict__ scale,       // (NB)
    const float* __restrict__ trans,       // (NB*3) flat
    float* __restrict__ vout)              // (NB, NV, 3)
{
    __shared__ __align__(16) char smem[81920];          // 80 KB total
    // A bufs: smem + a*16384 (a=0,1,2); B bufs: smem + 49152 + b*16384
    #define SA(a) ((_Float16*)(smem + (a)*16384))
    #define SB(b) ((_Float16*)(smem + 49152 + (b)*16384))

    const int t    = threadIdx.x;
    const int lane = t & 63;
    const int wid  = t >> 6;               // 0..7
    const int ln   = lane & 15;
    const int kq   = lane >> 4;
    const int wm   = wid & 1;              // m-half (64 rows)
    const int wn   = wid >> 1;             // n-quarter (32 cols)

    // bijective XCD swizzle (m204): nwg=1236, q=154, r=4
    const int q8 = GRID_GEMM >> 3;         // 154
    const int r8 = GRID_GEMM & 7;          // 4
    const int xcd = blockIdx.x & 7;
    const int idx = blockIdx.x >> 3;
    const int wgid = (xcd < r8 ? xcd*(q8+1) : r8*(q8+1) + (xcd-r8)*q8) + idx;

    const int mt = wgid / NBLK;
    const int nb = wgid - mt*NBLK;

    const _Float16* Ag = Ap + (size_t)mt*(KS*4096);
    const _Float16* Bg = Bp + (size_t)nb*(KS*4096);

    // fragment read offsets (bank-swizzled; 2-way conflict = free)
    const int csl = kq ^ ((ln >> 1) & 3);
    const int afo = (wm*64 + ln)*32 + csl*8;   // + mi*512 + half*4096
    const int bfo = (wn*32 + ln)*32 + csl*8;   // + ni*512 + half*4096

    f32x4 acc[4][2];
    #pragma unroll
    for (int mi = 0; mi < 4; ++mi)
        #pragma unroll
        for (int ni = 0; ni < 2; ++ni)
            acc[mi][ni] = (f32x4){0.f, 0.f, 0.f, 0.f};

    // stage one merged (64-k) buffer = two consecutive ks panels, 2 instrs
    #define STAGE_A(a, j2) do { \
        GL16(Ag + (2*(j2)  )*4096 + t*8, SA(a) +        wid*512); \
        GL16(Ag + (2*(j2)+1)*4096 + t*8, SA(a) + 4096 + wid*512); } while (0)
    #define STAGE_B(bf_, j2) do { \
        GL16(Bg + (2*(j2)  )*4096 + t*8, SB(bf_) +        wid*512); \
        GL16(Bg + (2*(j2)+1)*4096 + t*8, SB(bf_) + 4096 + wid*512); } while (0)

    auto compute = [&](int ba, int bb) {
        const _Float16* pa = SA(ba);
        const _Float16* pb = SB(bb);
        #pragma unroll
        for (int half = 0; half < 2; ++half) {
            f16x8 af[4], bf[2];
            #pragma unroll
            for (int mi = 0; mi < 4; ++mi)
                af[mi] = *(const f16x8*)&pa[half*4096 + afo + mi*512];
            #pragma unroll
            for (int ni = 0; ni < 2; ++ni)
                bf[ni] = *(const f16x8*)&pb[half*4096 + bfo + ni*512];
            __builtin_amdgcn_s_setprio(1);
            #pragma unroll
            for (int mi = 0; mi < 4; ++mi)
                #pragma unroll
                for (int ni = 0; ni < 2; ++ni)
                    acc[mi][ni] = __builtin_amdgcn_mfma_f32_16x16x32_f16(
                        af[mi], bf[ni], acc[mi][ni], 0, 0, 0);
            __builtin_amdgcn_s_setprio(0);
        }
    };

    // step j: wait vmcnt(2) -> A(j),B(j) complete, A(j+1) stays in flight;
    // barrier; stage B(j+1), A(j+2); compute j.
    #define STEP(j, bBn, bAn, bAc, bBc) do { \
        asm volatile("s_waitcnt vmcnt(2)" ::: "memory"); \
        __builtin_amdgcn_s_barrier(); \
        STAGE_B(bBn, (j) + 1); \
        STAGE_A(bAn, (j) + 2); \
        compute(bAc, bBc); } while (0)

    // prologue: B(0), A(0), A(1) in flight (6 load instrs)
    STAGE_B(0, 0);
    STAGE_A(0, 0);
    STAGE_A(1, 1);

    // steps 0..6 (consume A j%3, B j%2; stage B(j+1)->(j+1)%2, A(j+2)->(j+2)%3)
    STEP(0, 1, 2, 0, 0);
    STEP(1, 0, 0, 1, 1);
    STEP(2, 1, 1, 2, 0);
    STEP(3, 0, 2, 0, 1);
    STEP(4, 1, 0, 1, 0);
    STEP(5, 0, 1, 2, 1);
    STEP(6, 1, 2, 0, 0);
    // step 7: wait; stage B(8); compute (a1,b1). In flight after: A(8),B(8).
    asm volatile("s_waitcnt vmcnt(2)" ::: "memory");
    __builtin_amdgcn_s_barrier();
    STAGE_B(0, 8);
    compute(1, 1);
    // step 8: drain; compute (a2,b0)
    asm volatile("s_waitcnt vmcnt(0)" ::: "memory");
    __builtin_amdgcn_s_barrier();
    compute(2, 0);

    #undef STEP
    #undef STAGE_A
    #undef STAGE_B

    // ---- coalesced transpose epilogue (reuses the dead K-loop LDS) --------
    // Ct[64][132] f32 (33792 B), es_l[128] (@33792), etr_l[128] (@34304)
    float* Ct    = (float*)smem;
    float* es_l  = (float*)(smem + 33792);
    float* etr_l = (float*)(smem + 34304);

    const int vgA = t/3, crA = t - 3*vgA;  // element e = t (t < 384)

    #pragma unroll 1
    for (int h = 0; h < 2; ++h) {
        __syncthreads();                   // K-loop bufs / prev half dead
        if ((wn >> 1) == h) {
            // this half's columns live in waves with wn in {2h, 2h+1}
            #pragma unroll
            for (int mi = 0; mi < 4; ++mi)
                #pragma unroll
                for (int ni = 0; ni < 2; ++ni)
                    *(f32x4*)&Ct[((wn&1)*32 + ni*16 + ln)*132
                                 + wm*64 + mi*16 + kq*4] = acc[mi][ni];
        }
        if (h == 0 && t < 128) {
            int n = nb*128 + t;
            es_l[t]  = scale[n/3];
            etr_l[t] = trans[n];
        }
        __syncthreads();

        const int n0   = nb*128 + h*64;
        const int bq0  = n0/3;
        const int off0 = 3*bq0 - n0;       // in {-2,-1,0}
        const int bqN  = (n0 + 63)/3 - bq0 + 1;

        #pragma unroll 1
        for (int bqi = 0; bqi < bqN; ++bqi) {
            const long long base = (long long)(bq0 + bqi)*(NV*3)
                                 + (long long)mt*384;
            if (t < 384) {   // element e = t: addr = base + t, fully coalesced
                int nrel = off0 + 3*bqi + crA;
                if (nrel >= 0 && nrel < 64 && mt*128 + vgA < NV) {
                    int nf = h*64 + nrel;
                    vout[base + t] =
                        Ct[nrel*132 + vgA]*es_l[nf] + etr_l[nf];
                }
            }
        }
    }
    #undef SA
    #undef SB
}

extern "C" void kernel_launch(void* const* d_in, const int* in_sizes, int n_in,
                              void* d_out, int out_size, void* d_ws, size_t ws_size,
                              hipStream_t stream) {
    const float* pose         = (const float*)d_in[0];
    const float* bone_lengths = (const float*)d_in[1];
    const float* cbl          = (const float*)d_in[2];
    const float* trans        = (const float*)d_in[3];
    const float* scale        = (const float*)d_in[4];
    const float* v_template   = (const float*)d_in[5];
    const float* t_pose       = (const float*)d_in[6];
    const float* weights      = (const float*)d_in[7];
    const int*   parent       = (const int*)d_in[8];
    const int*   bone_mapper  = (const int*)d_in[9];

    float* vout = (float*)d_out;                          // (NB,NV,3)
    float* jout = vout + (size_t)NB*NV*3;                 // (NB,NJ,3)

    _Float16* Ap = (_Float16*)d_ws;                       // 949248*16 B = 15.2 MB
    _Float16* Bp = Ap + (size_t)APREP_SLOTS*8;            // 12*18*512*16 B = 1.69 MB

    prep_kernel<<<NB + MTILES*KS, 256, 0, stream>>>(
        pose, bone_lengths, cbl, trans, scale, v_template, t_pose,
        parent, bone_mapper, weights, Ap, Bp, jout);

    gemm_kernel<<<GRID_GEMM, 512, 0, stream>>>(Ap, Bp, scale, trans, vout);
}

// Round 10
// 144.225 us; speedup vs baseline: 1.0217x; 1.0217x over previous
//
#include <hip/hip_runtime.h>
#include <math.h>

#define NJ 140
#define NV 13059
#define NB 512
#define NBONES 28

#define MTILES 103                    // 103*128 = 13184 >= NV
#define NBLK 12                       // 1536 / 128
#define KS 18                         // K = 576 = 18*32
#define GRID_GEMM (MTILES*NBLK)       // 1236

#define APREP_SLOTS (MTILES*KS*512)   // 949248 f16x8 slots

typedef _Float16 f16x8 __attribute__((ext_vector_type(8)));
typedef float    f32x4 __attribute__((ext_vector_type(4)));

// async global->LDS DMA, 16 B per lane; lds base must be wave-uniform
#define GL16(gp, lp) __builtin_amdgcn_global_load_lds( \
    (const __attribute__((address_space(1))) unsigned int*)(gp), \
    (__attribute__((address_space(3))) unsigned int*)(lp), 16, 0, 0)

// ---------------- Kernel 1: fused prep (kin + A-prep) ----------------------
// Panel layout (both A and B), bank-swizzled for conflict-free ds_read_b128:
// panel[tile][ks][slot = row*4 + cs][8 f16], slot cs holds chunk
// ci = cs ^ ((row>>1)&3), i.e. elements [row][k = ks*32 + ci*8 .. +7].
// blocks [0,NB): kinematics for batch b -> packed B panels + jout
// blocks [NB, NB+MTILES*KS): A[v][k] = w[v,j]*{x,y,z,1}, one (mt,ks) per block
__global__ __launch_bounds__(256) void prep_kernel(
    const float* __restrict__ pose,         // (NB, NJ*3)
    const float* __restrict__ bone_lengths, // (NB, NBONES)
    const float* __restrict__ cbl,          // (NB)
    const float* __restrict__ trans,        // (NB, 3)
    const float* __restrict__ scale,        // (NB)
    const float* __restrict__ v_template,   // (NV, 3)
    const float* __restrict__ t_pose,       // (NJ, 3)
    const int*   __restrict__ parent,       // (NJ)
    const int*   __restrict__ bone_mapper,  // (NJ)
    const float* __restrict__ weights,      // (NV, NJ)
    _Float16* __restrict__ Ap,              // ws: (MTILES, KS, 512, 8)
    _Float16* __restrict__ Bp,              // ws: (NBLK, KS, 512, 8)
    float* __restrict__ jout)               // (NB, NJ, 3)
{
    const int t = threadIdx.x;

    if (blockIdx.x >= NB) {
        // ---- A prep: one (mt, ks) panel slice per block ----
        const int id  = blockIdx.x - NB;       // = mt*KS + ks
        const int mt  = id / KS;
        const int ks  = id - mt*KS;
        const int row = t >> 1;
        const int q   = t & 1;
        const int v   = mt*128 + row;
        const int j0  = ks*8 + q*4;
        const int s   = (row >> 1) & 3;

        f16x8 oA, oB;                          // chunks ci=2q and ci=2q+1
        #pragma unroll
        for (int i = 0; i < 8; ++i) { oA[i] = (_Float16)0.f; oB[i] = (_Float16)0.f; }

        if (v < NV && j0 + 3 < NJ) {           // NJ%8==4 -> per-quad all-or-nothing
            float xv = v_template[v*3+0];
            float yv = v_template[v*3+1];
            float zv = v_template[v*3+2];
            const float4 w4 = *(const float4*)(weights + (size_t)v*NJ + j0);
            oA[0] = (_Float16)(w4.x*xv); oA[1] = (_Float16)(w4.x*yv);
            oA[2] = (_Float16)(w4.x*zv); oA[3] = (_Float16)w4.x;
            oA[4] = (_Float16)(w4.y*xv); oA[5] = (_Float16)(w4.y*yv);
            oA[6] = (_Float16)(w4.y*zv); oA[7] = (_Float16)w4.y;
            oB[0] = (_Float16)(w4.z*xv); oB[1] = (_Float16)(w4.z*yv);
            oB[2] = (_Float16)(w4.z*zv); oB[3] = (_Float16)w4.z;
            oB[4] = (_Float16)(w4.w*xv); oB[5] = (_Float16)(w4.w*yv);
            oB[6] = (_Float16)(w4.w*zv); oB[7] = (_Float16)w4.w;
        }
        // slot cs holds chunk ci = cs ^ s  => cs(2q)=2q^s, cs(2q+1)=cs(2q)^1
        const int base = ((2*q) ^ s) & ~1;     // even slot of the pair
        _Float16* dst = Ap + (((size_t)id)*512 + row*4 + base)*8;
        if (s & 1) {                            // cs(2q) is odd
            *(f16x8*)dst       = oB;            // even slot = cs(2q+1)
            *(f16x8*)(dst + 8) = oA;            // odd slot  = cs(2q)
        } else {
            *(f16x8*)dst       = oA;
            *(f16x8*)(dst + 8) = oB;
        }
        return;
    }

    // ---- kinematics for batch b = blockIdx.x ----
    __shared__ float M0[NJ][12];
    __shared__ float M1[NJ][12];
    __shared__ int   a0[NJ];
    __shared__ int   a1[NJ];

    const int b = blockIdx.x;

    if (t < NJ) {
        const int j = t;
        float z = pose[b*(NJ*3) + 3*j + 0];
        float y = pose[b*(NJ*3) + 3*j + 1];
        float x = pose[b*(NJ*3) + 3*j + 2];
        float cx = cosf(x), sx = sinf(x);
        float cy = cosf(y), sy = sinf(y);
        float cz = cosf(z), sz = sinf(z);
        float r00 = cz*cy;
        float r01 = cz*sy*sx - sz*cx;
        float r02 = cz*sy*cx + sz*sx;
        float r10 = sz*cy;
        float r11 = sz*sy*sx + cz*cx;
        float r12 = sz*sy*cx - cz*sx;
        float r20 = -sy;
        float r21 = cy*sx;
        float r22 = cy*cx;
        float t0, t1, t2;
        int p = parent[j];
        if (j == 0) {
            t0 = t_pose[0]; t1 = t_pose[1]; t2 = t_pose[2];
        } else {
            float ox = t_pose[3*j+0] - t_pose[3*p+0];
            float oy = t_pose[3*j+1] - t_pose[3*p+1];
            float oz = t_pose[3*j+2] - t_pose[3*p+2];
            float s;
            if (j == 1) {
                s = cbl[b];
            } else {
                int blid = bone_mapper[j];
                if (blid >= 0) {
                    float bv = bone_lengths[b*NBONES + blid];
                    s = 2.0f / (1.0f + expf(-bv*0.2f));   // 2*sigmoid(x/5)
                } else {
                    s = 1.0f;
                }
            }
            t0 = ox*s; t1 = oy*s; t2 = oz*s;
        }
        M0[j][0]=r00; M0[j][1]=r01; M0[j][2]=r02;  M0[j][3]=t0;
        M0[j][4]=r10; M0[j][5]=r11; M0[j][6]=r12;  M0[j][7]=t1;
        M0[j][8]=r20; M0[j][9]=r21; M0[j][10]=r22; M0[j][11]=t2;
        a0[j] = (j == 0) ? -1 : p;
    }
    __syncthreads();

    float* src = &M0[0][0]; float* dst = &M1[0][0];
    int* as = a0; int* ad = a1;
    for (int r = 0; r < 8; ++r) {
        if (t < NJ) {
            int a = as[t];
            const float* Mi = src + t*12;
            float* Do = dst + t*12;
            if (a >= 0) {
                const float* Mp = src + a*12;
                #pragma unroll
                for (int m = 0; m < 3; ++m) {
                    float p0 = Mp[m*4+0], p1 = Mp[m*4+1], p2 = Mp[m*4+2], p3 = Mp[m*4+3];
                    Do[m*4+0] = p0*Mi[0] + p1*Mi[4] + p2*Mi[8];
                    Do[m*4+1] = p0*Mi[1] + p1*Mi[5] + p2*Mi[9];
                    Do[m*4+2] = p0*Mi[2] + p1*Mi[6] + p2*Mi[10];
                    Do[m*4+3] = p0*Mi[3] + p1*Mi[7] + p2*Mi[11] + p3;
                }
                ad[t] = as[a];
            } else {
                #pragma unroll
                for (int e = 0; e < 12; ++e) Do[e] = Mi[e];
                ad[t] = -1;
            }
        }
        __syncthreads();
        float* tf = src; src = dst; dst = tf;
        int* ti = as; as = ad; ad = ti;
    }

    // G_rel (fp32) into the spare LDS buffer, then pack to B panels
    float* grl = dst;   // dst != src after even # of swaps
    if (t < NJ) {
        const int j = t;
        const float* G = src + j*12;
        float sb = scale[b];
        float tr0 = trans[b*3+0], tr1 = trans[b*3+1], tr2 = trans[b*3+2];
        float* jo = jout + ((size_t)b*NJ + j)*3;
        jo[0] = G[3]*sb  + tr0;
        jo[1] = G[7]*sb  + tr1;
        jo[2] = G[11]*sb + tr2;
        float jx = t_pose[3*j+0], jy = t_pose[3*j+1], jz = t_pose[3*j+2];
        #pragma unroll
        for (int c = 0; c < 3; ++c) {
            float g0 = G[c*4+0], g1 = G[c*4+1], g2 = G[c*4+2];
            float g3 = G[c*4+3] - (g0*jx + g1*jy + g2*jz);
            grl[j*12 + c*4 + 0] = g0;
            grl[j*12 + c*4 + 1] = g1;
            grl[j*12 + c*4 + 2] = g2;
            grl[j*12 + c*4 + 3] = g3;
        }
    }
    __syncthreads();

    // pack: 3 rows x 18 ks x 4 ci = 216 f16x8 slots (swizzled)
    if (t < 216) {
        int c  = t / 72;
        int rr = t - c*72;
        int ks = rr >> 2;
        int ci = rr & 3;
        int nrow = b*3 + c;
        int nbp = nrow >> 7;
        int rl = nrow & 127;
        int j0 = ks*8 + ci*2;
        f16x8 o;
        #pragma unroll
        for (int i = 0; i < 8; ++i) o[i] = (_Float16)0.f;
        if (j0 < NJ) {
            o[0] = (_Float16)grl[j0*12 + c*4 + 0];
            o[1] = (_Float16)grl[j0*12 + c*4 + 1];
            o[2] = (_Float16)grl[j0*12 + c*4 + 2];
            o[3] = (_Float16)grl[j0*12 + c*4 + 3];
        }
        if (j0 + 1 < NJ) {
            o[4] = (_Float16)grl[(j0+1)*12 + c*4 + 0];
            o[5] = (_Float16)grl[(j0+1)*12 + c*4 + 1];
            o[6] = (_Float16)grl[(j0+1)*12 + c*4 + 2];
            o[7] = (_Float16)grl[(j0+1)*12 + c*4 + 3];
        }
        int cs = ci ^ ((rl >> 1) & 3);
        *(f16x8*)(Bp + ((size_t)(nbp*KS + ks)*512 + rl*4 + cs)*8) = o;
    }
}

// ---------------- Kernel 2: 8-wave ring GEMM (best measured: R6) -----------
// 1236 blocks x 512 thr (8 waves: 2m x 4n), tile 128x128, BK=32, 18 K-steps.
// Counted-vmcnt asymmetric ring (A 3-buf lead-2, B 2-buf lead-1), 40 KB LDS
// -> 4 blocks/CU = 24 waves/CU, setprio around MFMA, coalesced transpose
// epilogue. Session exoneration matrix (R0-R9): schedule depth, TLP, BK=64,
// XCD locality, and prep fusion are all within ±3 us of this config; the
// one large win was the coalesced epilogue (-17 us). Remaining gemm gap to
// the ~28 us floor requires the 256^2/8-phase co-designed stack (catalog
// T2-T5 gate), out of proportion to the ~100 us fixed harness overhead.
__global__ __launch_bounds__(512, 6) void gemm_kernel(
    const _Float16* __restrict__ Ap,       // (MTILES, KS, 512, 8)
    const _Float16* __restrict__ Bp,       // (NBLK, KS, 512, 8)
    const float* __restrict__ scale,       // (NB)
    const float* __restrict__ trans,       // (NB*3) flat
    float* __restrict__ vout)              // (NB, NV, 3)
{
    __shared__ __align__(16) char smem[40960];          // 40 KB total
    _Float16 (*sA)[4096] = (_Float16(*)[4096])smem;             // 3 bufs, 24 KB
    _Float16 (*sB)[4096] = (_Float16(*)[4096])(smem + 24576);   // 2 bufs, 16 KB

    const int t    = threadIdx.x;
    const int lane = t & 63;
    const int wid  = t >> 6;               // 0..7
    const int ln   = lane & 15;
    const int kq   = lane >> 4;
    const int wm   = wid & 1;              // m-half (64 rows)
    const int wn   = wid >> 1;             // n-quarter (32 cols)

    // bijective XCD swizzle (m204): nwg=1236, q=154, r=4
    const int q8 = GRID_GEMM >> 3;         // 154
    const int r8 = GRID_GEMM & 7;          // 4
    const int xcd = blockIdx.x & 7;
    const int idx = blockIdx.x >> 3;
    const int wgid = (xcd < r8 ? xcd*(q8+1) : r8*(q8+1) + (xcd-r8)*q8) + idx;

    const int mt = wgid / NBLK;
    const int nb = wgid - mt*NBLK;

    const _Float16* Ag = Ap + (size_t)mt*(KS*4096);
    const _Float16* Bg = Bp + (size_t)nb*(KS*4096);

    // fragment read offsets (bank-swizzled; 2-way conflict = free)
    const int csl = kq ^ ((ln >> 1) & 3);
    const int afo = (wm*64 + ln)*32 + csl*8;   // + mi*512 (mi 0..3)
    const int bfo = (wn*32 + ln)*32 + csl*8;   // + ni*512 (ni 0..1)

    f32x4 acc[4][2];
    #pragma unroll
    for (int mi = 0; mi < 4; ++mi)
        #pragma unroll
        for (int ni = 0; ni < 2; ++ni)
            acc[mi][ni] = (f32x4){0.f, 0.f, 0.f, 0.f};

    // ONE load instr per 8 KB buffer: 512 lanes x 16 B. LDS base wave-uniform.
    #define STAGE_A(buf, ksv) GL16(Ag + (ksv)*4096 + t*8, &sA[buf][wid*512])
    #define STAGE_B(buf, ksv) GL16(Bg + (ksv)*4096 + t*8, &sB[buf][wid*512])

    auto compute = [&](int ba, int bb) {
        f16x8 af[4], bf[2];
        #pragma unroll
        for (int mi = 0; mi < 4; ++mi)
            af[mi] = *(const f16x8*)&sA[ba][afo + mi*512];
        #pragma unroll
        for (int ni = 0; ni < 2; ++ni)
            bf[ni] = *(const f16x8*)&sB[bb][bfo + ni*512];
        __builtin_amdgcn_s_setprio(1);
        #pragma unroll
        for (int mi = 0; mi < 4; ++mi)
            #pragma unroll
            for (int ni = 0; ni < 2; ++ni)
                acc[mi][ni] = __builtin_amdgcn_mfma_f32_16x16x32_f16(
                    af[mi], bf[ni], acc[mi][ni], 0, 0, 0);
        __builtin_amdgcn_s_setprio(0);
    };

    // step j: wait (completes A(j),B(j); A(j+1) stays in flight); barrier;
    // stage B(j+1), A(j+2); compute j.
    #define STEP(j, bBn, bAn, bAc, bBc) do { \
        asm volatile("s_waitcnt vmcnt(1)" ::: "memory"); \
        __builtin_amdgcn_s_barrier(); \
        STAGE_B(bBn, (j) + 1); \
        STAGE_A(bAn, (j) + 2); \
        compute(bAc, bBc); } while (0)

    // prologue: B(0), A(0), A(1) in flight (3 load instrs)
    STAGE_B(0, 0);
    STAGE_A(0, 0);
    STAGE_A(1, 1);

    #pragma unroll 1
    for (int i = 0; i < 12; i += 6) {      // steps 0..11
        STEP(i + 0, 1, 2, 0, 0);
        STEP(i + 1, 0, 0, 1, 1);
        STEP(i + 2, 1, 1, 2, 0);
        STEP(i + 3, 0, 2, 0, 1);
        STEP(i + 4, 1, 0, 1, 0);
        STEP(i + 5, 0, 1, 2, 1);
    }
    // steps 12..15 (same ring phase as 0..3)
    STEP(12, 1, 2, 0, 0);
    STEP(13, 0, 0, 1, 1);
    STEP(14, 1, 1, 2, 0);
    STEP(15, 0, 2, 0, 1);
    // step 16: in flight [A(16), B(16), A(17)] -> vmcnt(1); stage B(17)
    asm volatile("s_waitcnt vmcnt(1)" ::: "memory");
    __builtin_amdgcn_s_barrier();
    STAGE_B(1, 17);
    compute(1, 0);
    // step 17: drain
    asm volatile("s_waitcnt vmcnt(0)" ::: "memory");
    __builtin_amdgcn_s_barrier();
    compute(2, 1);

    #undef STEP
    #undef STAGE_A
    #undef STAGE_B

    // ---- coalesced transpose epilogue (reuses the dead K-loop LDS) --------
    // Ct[64][132] f32 (33792 B), es_l[128] (@33792), etr_l[128] (@34304)
    float* Ct    = (float*)smem;
    float* es_l  = (float*)(smem + 33792);
    float* etr_l = (float*)(smem + 34304);

    const int vgA = t/3, crA = t - 3*vgA;  // element e = t (t < 384)

    #pragma unroll 1
    for (int h = 0; h < 2; ++h) {
        __syncthreads();                   // K-loop bufs / prev half dead
        if ((wn >> 1) == h) {
            // this half's columns live in waves with wn in {2h, 2h+1}
            #pragma unroll
            for (int mi = 0; mi < 4; ++mi)
                #pragma unroll
                for (int ni = 0; ni < 2; ++ni)
                    *(f32x4*)&Ct[((wn&1)*32 + ni*16 + ln)*132
                                 + wm*64 + mi*16 + kq*4] = acc[mi][ni];
        }
        if (h == 0 && t < 128) {
            int n = nb*128 + t;
            es_l[t]  = scale[n/3];
            etr_l[t] = trans[n];
        }
        __syncthreads();

        const int n0   = nb*128 + h*64;
        const int bq0  = n0/3;
        const int off0 = 3*bq0 - n0;       // in {-2,-1,0}
        const int bqN  = (n0 + 63)/3 - bq0 + 1;

        #pragma unroll 1
        for (int bqi = 0; bqi < bqN; ++bqi) {
            const long long base = (long long)(bq0 + bqi)*(NV*3)
                                 + (long long)mt*384;
            if (t < 384) {   // element e = t: addr = base + t, fully coalesced
                int nrel = off0 + 3*bqi + crA;
                if (nrel >= 0 && nrel < 64 && mt*128 + vgA < NV) {
                    int nf = h*64 + nrel;
                    vout[base + t] =
                        Ct[nrel*132 + vgA]*es_l[nf] + etr_l[nf];
                }
            }
        }
    }
}

extern "C" void kernel_launch(void* const* d_in, const int* in_sizes, int n_in,
                              void* d_out, int out_size, void* d_ws, size_t ws_size,
                              hipStream_t stream) {
    const float* pose         = (const float*)d_in[0];
    const float* bone_lengths = (const float*)d_in[1];
    const float* cbl          = (const float*)d_in[2];
    const float* trans        = (const float*)d_in[3];
    const float* scale        = (const float*)d_in[4];
    const float* v_template   = (const float*)d_in[5];
    const float* t_pose       = (const float*)d_in[6];
    const float* weights      = (const float*)d_in[7];
    const int*   parent       = (const int*)d_in[8];
    const int*   bone_mapper  = (const int*)d_in[9];

    float* vout = (float*)d_out;                          // (NB,NV,3)
    float* jout = vout + (size_t)NB*NV*3;                 // (NB,NJ,3)

    _Float16* Ap = (_Float16*)d_ws;                       // 949248*16 B = 15.2 MB
    _Float16* Bp = Ap + (size_t)APREP_SLOTS*8;            // 12*18*512*16 B = 1.69 MB

    prep_kernel<<<NB + MTILES*KS, 256, 0, stream>>>(
        pose, bone_lengths, cbl, trans, scale, v_template, t_pose,
        parent, bone_mapper, weights, Ap, Bp, jout);

    gemm_kernel<<<GRID_GEMM, 512, 0, stream>>>(Ap, Bp, scale, trans, vout);
}